// Round 6
// baseline (182.264 us; speedup 1.0000x reference)
//
#include <hip/hip_runtime.h>
#include <math.h>

// EnhancedTripletLoss, B=8192, D=256, 8 classes.
// R6: 512-thread blocks, 8 waves (4x2), wave tile 32x64 -> per-thread state
// ~100 regs (no spill) and 16 waves/CU. A-tile (128x256 bf16, 64 KB) in LDS
// staged once; B streamed global->reg from fragment-major bf16; packed u32
// selection keys ((q(v)<<13)|j). Exact fp32 recompute of mined distances.

typedef __attribute__((ext_vector_type(8))) short short8;
typedef __attribute__((ext_vector_type(4))) float floatx4;

#define B_N 8192
#define D_K 256
#define NP  16

__device__ __forceinline__ unsigned short f2bf_rne(float f) {
  unsigned u = __float_as_uint(f);
  u += 0x7FFFu + ((u >> 16) & 1u);
  return (unsigned short)(u >> 16);
}

// ---- split to bf16 fragment-major + row norms + zero accumulators ----
// Tile (16 rows x 32 k) = 512 ushorts at [tile_row][tk][lane*8+j]:
// lane = quad*16 + m, row = 16*tile_row + m, k = 32*tk + quad*8 + j.
__global__ void k_split(const float* __restrict__ x, unsigned short* __restrict__ xhf,
                        float* __restrict__ sq, float* __restrict__ sum,
                        int* __restrict__ cnt, int* __restrict__ done) {
  __shared__ float sw[64];
  const int tid  = threadIdx.x;
  const int lane = tid & 63;
  const int w    = tid >> 6;
  const int b    = blockIdx.x;        // tile_row
  const int m    = lane & 15;
  const int quad = lane >> 4;
  const int row  = b * 16 + m;

  float s = 0.f;
#pragma unroll
  for (int h = 0; h < 2; ++h) {
    int tk = w + h * 4;
    int kk = tk * 32 + quad * 8;
    float4 f0 = *reinterpret_cast<const float4*>(x + (size_t)row * D_K + kk);
    float4 f1 = *reinterpret_cast<const float4*>(x + (size_t)row * D_K + kk + 4);
    s += f0.x * f0.x + f0.y * f0.y + f0.z * f0.z + f0.w * f0.w;
    s += f1.x * f1.x + f1.y * f1.y + f1.z * f1.z + f1.w * f1.w;
    ushort4 lo, hi;
    lo.x = f2bf_rne(f0.x); lo.y = f2bf_rne(f0.y); lo.z = f2bf_rne(f0.z); lo.w = f2bf_rne(f0.w);
    hi.x = f2bf_rne(f1.x); hi.y = f2bf_rne(f1.y); hi.z = f2bf_rne(f1.z); hi.w = f2bf_rne(f1.w);
    size_t o = ((size_t)b * 8 + tk) * 512 + lane * 8;
    *reinterpret_cast<ushort4*>(xhf + o)     = lo;
    *reinterpret_cast<ushort4*>(xhf + o + 4) = hi;
  }
  s += __shfl_xor(s, 16);
  s += __shfl_xor(s, 32);
  if (quad == 0) sw[w * 16 + m] = s;
  __syncthreads();
  if (tid < 16) sq[b * 16 + tid] = sw[tid] + sw[16 + tid] + sw[32 + tid] + sw[48 + tid];
  if (b == 0 && tid == 0) { *sum = 0.f; *cnt = 0; *done = 0; }
}

// ---- MFMA Gram + hard mining: 8 waves, wave tile 32x64, no spill ----
__global__ __launch_bounds__(512, 4) void k_mine6(
    const unsigned short* __restrict__ xhf, const int* __restrict__ lab,
    const float* __restrict__ sq,
    unsigned* __restrict__ pk, unsigned* __restrict__ nk) {
  __shared__ unsigned short Alds[8 * 8 * 512];   // 64 KB: [mtile 8][tk 8][512]

  const int tid  = threadIdx.x;
  const int lane = tid & 63;
  const int w    = tid >> 6;          // 0..7
  const int wi   = w >> 1;            // 0..3 : 32-anchor band
  const int wj   = w & 1;             // 0..1 : 64-cand half
  const int quad = lane >> 4, l15 = lane & 15;
  const int i0   = blockIdx.x * 128;
  const int by   = blockIdx.y;

  // stage A: contiguous 64 KB copy (already fragment-major)
  {
    const short8* src = reinterpret_cast<const short8*>(xhf + (size_t)blockIdx.x * 32768);
    short8* dst = reinterpret_cast<short8*>(Alds);
#pragma unroll
    for (int it = 0; it < 8; ++it) dst[it * 512 + tid] = src[it * 512 + tid];
  }

  unsigned pkey[8], nkey[8];
  unsigned lip = 0;                   // 8 row labels, 4 bits each
#pragma unroll
  for (int r = 0; r < 8; ++r) {
    pkey[r] = 0u; nkey[r] = 0xFFFFFFFFu;
    int ir = i0 + wi * 32 + (r >> 2) * 16 + quad * 4 + (r & 3);
    lip |= ((unsigned)lab[ir] & 0xFu) << (r * 4);
  }
  __syncthreads();   // the only barrier

  const unsigned short* Bw = xhf + ((size_t)(by * 64 + wj * 4) * 8) * 512 + lane * 8;
  const unsigned short* Aw = Alds + (size_t)(wi * 2) * 4096 + lane * 8;

  for (int sub = 0; sub < 8; ++sub) {
    floatx4 acc[8];
#pragma unroll
    for (int q = 0; q < 8; ++q) acc[q] = (floatx4)0.f;

#pragma unroll
    for (int tk = 0; tk < 8; ++tk) {
      short8 Bf[4];
#pragma unroll
      for (int nt = 0; nt < 4; ++nt)
        Bf[nt] = *reinterpret_cast<const short8*>(Bw + (size_t)(sub * 8 + nt) * 4096 + tk * 512);
#pragma unroll
      for (int mt = 0; mt < 2; ++mt) {
        short8 Af = *reinterpret_cast<const short8*>(Aw + (size_t)mt * 4096 + tk * 512);
#pragma unroll
        for (int nt = 0; nt < 4; ++nt)
          acc[mt * 4 + nt] = __builtin_amdgcn_mfma_f32_16x16x32_bf16(
              Af, Bf[nt], acc[mt * 4 + nt], 0, 0, 0);
      }
    }

    // selection on v = sq_j - 2*dot (monotone per anchor); key = (q(v)<<13)|j.
    // Self never wins argmax-pos (its v = -sq_i is the row minimum).
    const int j0 = by * 1024 + sub * 128 + wj * 64;
#pragma unroll
    for (int nt = 0; nt < 4; ++nt) {
      int      j  = j0 + nt * 16 + l15;
      unsigned jl = (unsigned)lab[j] & 0xFu;
      float    sj = sq[j];
#pragma unroll
      for (int r = 0; r < 8; ++r) {
        int mt = r >> 2, reg = r & 3;
        float v = fmaf(-2.f, acc[mt * 4 + nt][reg], sj);
        unsigned kq  = (unsigned)fmaf(v, 128.f, 262144.f);   // v in (-2048,2048)
        unsigned key = (kq << 13) | (unsigned)j;
        bool eq = (jl == ((lip >> (r * 4)) & 0xFu));
        unsigned pc = eq ? key : 0u;
        unsigned nc = eq ? 0xFFFFFFFFu : key;
        pkey[r] = pkey[r] > pc ? pkey[r] : pc;
        nkey[r] = nkey[r] < nc ? nkey[r] : nc;
      }
    }
  }

  // reduce across the 16 l15-lanes of each quad
#pragma unroll
  for (int r = 0; r < 8; ++r) {
    unsigned p = pkey[r], n = nkey[r];
#pragma unroll
    for (int m = 1; m < 16; m <<= 1) {
      unsigned op = (unsigned)__shfl_xor((int)p, m);
      unsigned on = (unsigned)__shfl_xor((int)n, m);
      p = p > op ? p : op;
      n = n < on ? n : on;
    }
    if (l15 == 0) {
      int ir = i0 + wi * 32 + (r >> 2) * 16 + quad * 4 + (r & 3);
      size_t idx = (size_t)(by * 2 + wj) * B_N + ir;
      pk[idx] = p;
      nk[idx] = n;
    }
  }
}

// ---- reduce partials + exact fp32 triplet distances + loss + final divide ----
__global__ void k_finish(const float* __restrict__ x,
                         const unsigned* __restrict__ pk, const unsigned* __restrict__ nk,
                         float* __restrict__ sum, int* __restrict__ cnt,
                         int* __restrict__ done, float* __restrict__ out) {
  __shared__ float ssum[4];
  __shared__ int   scnt[4];
  int w = threadIdx.x >> 6, lane = threadIdx.x & 63;
  float lsum = 0.f; int lcnt = 0;
  for (int it = 0; it < 8; ++it) {
    int a = (blockIdx.x * 4 + w) * 8 + it;
    unsigned p = 0u, n = 0xFFFFFFFFu;
    if (lane < NP) {
      p = pk[(size_t)lane * B_N + a];
      n = nk[(size_t)lane * B_N + a];
    }
#pragma unroll
    for (int m = 1; m < 16; m <<= 1) {
      unsigned op = (unsigned)__shfl_xor((int)p, m);
      unsigned on = (unsigned)__shfl_xor((int)n, m);
      p = p > op ? p : op;
      n = n < on ? n : on;
    }
    p = (unsigned)__shfl((int)p, 0);
    n = (unsigned)__shfl((int)n, 0);
    bool valid = (p != 0u) && (n != 0xFFFFFFFFu);
    int  pidx = valid ? (int)(p & 8191u) : 0;
    int  nidx = valid ? (int)(n & 8191u) : 0;

    float4 xa = *reinterpret_cast<const float4*>(x + (size_t)a * D_K + lane * 4);
    float4 xp = *reinterpret_cast<const float4*>(x + (size_t)pidx * D_K + lane * 4);
    float4 xn = *reinterpret_cast<const float4*>(x + (size_t)nidx * D_K + lane * 4);
    float dx, sp = 0.f, sn = 0.f;
    dx = xa.x - xp.x + 1e-6f; sp = fmaf(dx, dx, sp);
    dx = xa.y - xp.y + 1e-6f; sp = fmaf(dx, dx, sp);
    dx = xa.z - xp.z + 1e-6f; sp = fmaf(dx, dx, sp);
    dx = xa.w - xp.w + 1e-6f; sp = fmaf(dx, dx, sp);
    dx = xa.x - xn.x + 1e-6f; sn = fmaf(dx, dx, sn);
    dx = xa.y - xn.y + 1e-6f; sn = fmaf(dx, dx, sn);
    dx = xa.z - xn.z + 1e-6f; sn = fmaf(dx, dx, sn);
    dx = xa.w - xn.w + 1e-6f; sn = fmaf(dx, dx, sn);
#pragma unroll
    for (int o = 32; o > 0; o >>= 1) {
      sp += __shfl_down(sp, o, 64);
      sn += __shfl_down(sn, o, 64);
    }
    if (lane == 0 && valid) {
      float per = sqrtf(sp) - sqrtf(sn) + 0.3f;
      if (per > 0.f) lsum += per;
      lcnt += 1;
    }
  }
  if (lane == 0) { ssum[w] = lsum; scnt[w] = lcnt; }
  __syncthreads();
  if (threadIdx.x == 0) {
    atomicAdd(sum, ssum[0] + ssum[1] + ssum[2] + ssum[3]);
    atomicAdd(cnt, scnt[0] + scnt[1] + scnt[2] + scnt[3]);
    __threadfence();
    int prev = atomicAdd(done, 1);
    if (prev == gridDim.x - 1) {
      float s = atomicAdd(sum, 0.f);
      int   c = atomicAdd(cnt, 0);
      if (c < 1) c = 1;
      out[0] = s / (float)c;
    }
  }
}

extern "C" void kernel_launch(void* const* d_in, const int* in_sizes, int n_in,
                              void* d_out, int out_size, void* d_ws, size_t ws_size,
                              hipStream_t stream) {
  const float* x   = (const float*)d_in[0];
  const int*   lab = (const int*)d_in[1];
  float*       out = (float*)d_out;

  char* ws = (char*)d_ws;
  unsigned short* xhf = (unsigned short*)ws;                      // 4 MB
  float* sq = (float*)(ws + (size_t)4608 * 1024);                 // 32 KB
  char*  pb = ws + (size_t)4608 * 1024 + 65536;
  size_t seg = (size_t)NP * B_N * 4;                              // 512 KB each
  unsigned* pk  = (unsigned*)(pb + 0 * seg);
  unsigned* nk  = (unsigned*)(pb + 1 * seg);
  float* sum  = (float*)(pb + 2 * seg);
  int*   cnt  = (int*)(sum + 1);
  int*   done = (int*)(sum + 2);

  k_split<<<B_N / 16, 256, 0, stream>>>(x, xhf, sq, sum, cnt, done);
  dim3 g(B_N / 128, 8);
  k_mine6<<<g, 512, 0, stream>>>(xhf, lab, sq, pk, nk);
  k_finish<<<256, 256, 0, stream>>>(x, pk, nk, sum, cnt, done, out);
}

// Round 7
// 164.879 us; speedup vs baseline: 1.1054x; 1.1054x over previous
//
#include <hip/hip_runtime.h>
#include <math.h>

// EnhancedTripletLoss, B=8192, D=256, 8 classes.
// R7: R5 geometry (256 thr, 2x2 waves, wave tile 64x64, A-tile in LDS staged
// once) + depth-1 named B-prefetch (hides ~250cyc L2 latency under the
// 16-MFMA burst) + batched A ds_reads + pre-quantized row norms.
// Selection keys: key = (cvt(fmaf(-256,dot,sjq)) << 13) | j, pos umax / neg umin.
// Exact fp32 recompute of mined triplet distances in k_finish.

typedef __attribute__((ext_vector_type(8))) short short8;
typedef __attribute__((ext_vector_type(4))) float floatx4;

#define B_N 8192
#define D_K 256
#define NP  16

__device__ __forceinline__ unsigned short f2bf_rne(float f) {
  unsigned u = __float_as_uint(f);
  u += 0x7FFFu + ((u >> 16) & 1u);
  return (unsigned short)(u >> 16);
}

// ---- split to bf16 fragment-major + quantized row norms + zero accums ----
// Tile (16 rows x 32 k) = 512 ushorts at [tile_row][tk][lane*8+j]:
// lane = quad*16 + m, row = 16*tile_row + m, k = 32*tk + quad*8 + j.
__global__ void k_split(const float* __restrict__ x, unsigned short* __restrict__ xhf,
                        float* __restrict__ sqq, float* __restrict__ sum,
                        int* __restrict__ cnt, int* __restrict__ done) {
  __shared__ float sw[64];
  const int tid  = threadIdx.x;
  const int lane = tid & 63;
  const int w    = tid >> 6;
  const int b    = blockIdx.x;        // tile_row
  const int m    = lane & 15;
  const int quad = lane >> 4;
  const int row  = b * 16 + m;

  float s = 0.f;
#pragma unroll
  for (int h = 0; h < 2; ++h) {
    int tk = w + h * 4;
    int kk = tk * 32 + quad * 8;
    float4 f0 = *reinterpret_cast<const float4*>(x + (size_t)row * D_K + kk);
    float4 f1 = *reinterpret_cast<const float4*>(x + (size_t)row * D_K + kk + 4);
    s += f0.x * f0.x + f0.y * f0.y + f0.z * f0.z + f0.w * f0.w;
    s += f1.x * f1.x + f1.y * f1.y + f1.z * f1.z + f1.w * f1.w;
    ushort4 lo, hi;
    lo.x = f2bf_rne(f0.x); lo.y = f2bf_rne(f0.y); lo.z = f2bf_rne(f0.z); lo.w = f2bf_rne(f0.w);
    hi.x = f2bf_rne(f1.x); hi.y = f2bf_rne(f1.y); hi.z = f2bf_rne(f1.z); hi.w = f2bf_rne(f1.w);
    size_t o = ((size_t)b * 8 + tk) * 512 + lane * 8;
    *reinterpret_cast<ushort4*>(xhf + o)     = lo;
    *reinterpret_cast<ushort4*>(xhf + o + 4) = hi;
  }
  s += __shfl_xor(s, 16);
  s += __shfl_xor(s, 32);
  if (quad == 0) sw[w * 16 + m] = s;
  __syncthreads();
  if (tid < 16) {
    float t = sw[tid] + sw[16 + tid] + sw[32 + tid] + sw[48 + tid];
    sqq[b * 16 + tid] = fmaf(t, 128.f, 262144.f);   // pre-quantized for key calc
  }
  if (b == 0 && tid == 0) { *sum = 0.f; *cnt = 0; *done = 0; }
}

// ---- MFMA Gram + hard mining: A in LDS, B prefetched global->reg ----
__global__ __launch_bounds__(256, 2) void k_mine7(
    const unsigned short* __restrict__ xhf, const int* __restrict__ lab,
    const float* __restrict__ sqq,
    unsigned* __restrict__ pk, unsigned* __restrict__ nk) {
  __shared__ unsigned short Alds[8 * 8 * 512];   // 64 KB: [mtile 8][tk 8][512]

  const int tid  = threadIdx.x;
  const int lane = tid & 63;
  const int w    = tid >> 6;
  const int wi   = w >> 1, wj = w & 1;
  const int quad = lane >> 4, l15 = lane & 15;
  const int i0   = blockIdx.x * 128;
  const int by   = blockIdx.y;

  // stage A: one contiguous 64 KB copy (already fragment-major)
  {
    const short8* src = reinterpret_cast<const short8*>(xhf + (size_t)blockIdx.x * 32768);
    short8* dst = reinterpret_cast<short8*>(Alds);
#pragma unroll
    for (int it = 0; it < 16; ++it) dst[it * 256 + tid] = src[it * 256 + tid];
  }

  unsigned pkey[16], nkey[16];
  unsigned lip0 = 0, lip1 = 0;
#pragma unroll
  for (int r = 0; r < 16; ++r) {
    pkey[r] = 0u; nkey[r] = 0xFFFFFFFFu;
    int ir = i0 + wi * 64 + (r >> 2) * 16 + quad * 4 + (r & 3);
    unsigned lv = (unsigned)lab[ir] & 0xFu;
    if (r < 8) lip0 |= lv << (r * 4); else lip1 |= lv << ((r - 8) * 4);
  }
  __syncthreads();   // the only barrier

  const unsigned short* Bw = xhf + ((size_t)(by * 64 + wj * 4) * 8) * 512 + lane * 8;
  const unsigned short* Aw = Alds + (size_t)wi * 32 * 512 + lane * 8;

  short8 Bf[4], Bn[4];
#pragma unroll
  for (int nt = 0; nt < 4; ++nt)
    Bf[nt] = *reinterpret_cast<const short8*>(Bw + nt * 4096);

  for (int sub = 0; sub < 8; ++sub) {
    const unsigned short* Bs = Bw + (size_t)sub * 32768;
    floatx4 acc[16];
#pragma unroll
    for (int q = 0; q < 16; ++q) acc[q] = (floatx4)0.f;

#pragma unroll
    for (int tk = 0; tk < 8; ++tk) {
      // prefetch t+1's B frags (tk==7 -> next sub's tk=0; sub==7 reads slack)
      const int c = tk + 1;
      const unsigned short* Bp = Bs + (c < 8 ? c * 512 : 32768);
#pragma unroll
      for (int nt = 0; nt < 4; ++nt)
        Bn[nt] = *reinterpret_cast<const short8*>(Bp + nt * 4096);

      short8 Af[4];
#pragma unroll
      for (int mt = 0; mt < 4; ++mt)
        Af[mt] = *reinterpret_cast<const short8*>(Aw + (size_t)(mt * 8 + tk) * 512);

#pragma unroll
      for (int mt = 0; mt < 4; ++mt)
#pragma unroll
        for (int nt = 0; nt < 4; ++nt)
          acc[mt * 4 + nt] = __builtin_amdgcn_mfma_f32_16x16x32_bf16(
              Af[mt], Bf[nt], acc[mt * 4 + nt], 0, 0, 0);

#pragma unroll
      for (int nt = 0; nt < 4; ++nt) Bf[nt] = Bn[nt];
    }

    // selection on v = sq_j - 2*dot (monotone per anchor).
    // key = (cvt(sjq - 256*dot) << 13) | j ; pos: umax, neg: umin.
    // Self never wins argmax-pos (its v = -sq_i is the per-row minimum).
    const int j0 = by * 1024 + sub * 128;
#pragma unroll
    for (int nt = 0; nt < 4; ++nt) {
      int      j  = j0 + wj * 64 + nt * 16 + l15;
      unsigned jl = (unsigned)lab[j] & 0xFu;
      float    sj = sqq[j];
#pragma unroll
      for (int r = 0; r < 16; ++r) {
        int mt = r >> 2, reg = r & 3;
        unsigned kq  = (unsigned)fmaf(-256.f, acc[mt * 4 + nt][reg], sj);
        unsigned key = (kq << 13) | (unsigned)j;
        unsigned lr  = (r < 8 ? (lip0 >> (r * 4)) : (lip1 >> ((r - 8) * 4))) & 0xFu;
        bool eq = (jl == lr);
        unsigned pc = eq ? key : 0u;
        unsigned nc = eq ? 0xFFFFFFFFu : key;
        pkey[r] = pkey[r] > pc ? pkey[r] : pc;
        nkey[r] = nkey[r] < nc ? nkey[r] : nc;
      }
    }
  }

  // reduce across the 16 l15-lanes of each quad
#pragma unroll
  for (int r = 0; r < 16; ++r) {
    unsigned p = pkey[r], n = nkey[r];
#pragma unroll
    for (int m = 1; m < 16; m <<= 1) {
      unsigned op = (unsigned)__shfl_xor((int)p, m);
      unsigned on = (unsigned)__shfl_xor((int)n, m);
      p = p > op ? p : op;
      n = n < on ? n : on;
    }
    if (l15 == 0) {
      int ir = i0 + wi * 64 + (r >> 2) * 16 + quad * 4 + (r & 3);
      size_t idx = (size_t)(by * 2 + wj) * B_N + ir;
      pk[idx] = p;
      nk[idx] = n;
    }
  }
}

// ---- reduce partials + exact fp32 triplet distances + loss + final divide ----
__global__ void k_finish(const float* __restrict__ x,
                         const unsigned* __restrict__ pk, const unsigned* __restrict__ nk,
                         float* __restrict__ sum, int* __restrict__ cnt,
                         int* __restrict__ done, float* __restrict__ out) {
  __shared__ float ssum[4];
  __shared__ int   scnt[4];
  int w = threadIdx.x >> 6, lane = threadIdx.x & 63;
  float lsum = 0.f; int lcnt = 0;
  for (int it = 0; it < 8; ++it) {
    int a = (blockIdx.x * 4 + w) * 8 + it;
    unsigned p = 0u, n = 0xFFFFFFFFu;
    if (lane < NP) {
      p = pk[(size_t)lane * B_N + a];
      n = nk[(size_t)lane * B_N + a];
    }
#pragma unroll
    for (int m = 1; m < 16; m <<= 1) {
      unsigned op = (unsigned)__shfl_xor((int)p, m);
      unsigned on = (unsigned)__shfl_xor((int)n, m);
      p = p > op ? p : op;
      n = n < on ? n : on;
    }
    p = (unsigned)__shfl((int)p, 0);
    n = (unsigned)__shfl((int)n, 0);
    bool valid = (p != 0u) && (n != 0xFFFFFFFFu);
    int  pidx = valid ? (int)(p & 8191u) : 0;
    int  nidx = valid ? (int)(n & 8191u) : 0;

    float4 xa = *reinterpret_cast<const float4*>(x + (size_t)a * D_K + lane * 4);
    float4 xp = *reinterpret_cast<const float4*>(x + (size_t)pidx * D_K + lane * 4);
    float4 xn = *reinterpret_cast<const float4*>(x + (size_t)nidx * D_K + lane * 4);
    float dx, sp = 0.f, sn = 0.f;
    dx = xa.x - xp.x + 1e-6f; sp = fmaf(dx, dx, sp);
    dx = xa.y - xp.y + 1e-6f; sp = fmaf(dx, dx, sp);
    dx = xa.z - xp.z + 1e-6f; sp = fmaf(dx, dx, sp);
    dx = xa.w - xp.w + 1e-6f; sp = fmaf(dx, dx, sp);
    dx = xa.x - xn.x + 1e-6f; sn = fmaf(dx, dx, sn);
    dx = xa.y - xn.y + 1e-6f; sn = fmaf(dx, dx, sn);
    dx = xa.z - xn.z + 1e-6f; sn = fmaf(dx, dx, sn);
    dx = xa.w - xn.w + 1e-6f; sn = fmaf(dx, dx, sn);
#pragma unroll
    for (int o = 32; o > 0; o >>= 1) {
      sp += __shfl_down(sp, o, 64);
      sn += __shfl_down(sn, o, 64);
    }
    if (lane == 0 && valid) {
      float per = sqrtf(sp) - sqrtf(sn) + 0.3f;
      if (per > 0.f) lsum += per;
      lcnt += 1;
    }
  }
  if (lane == 0) { ssum[w] = lsum; scnt[w] = lcnt; }
  __syncthreads();
  if (threadIdx.x == 0) {
    atomicAdd(sum, ssum[0] + ssum[1] + ssum[2] + ssum[3]);
    atomicAdd(cnt, scnt[0] + scnt[1] + scnt[2] + scnt[3]);
    __threadfence();
    int prev = atomicAdd(done, 1);
    if (prev == gridDim.x - 1) {
      float s = atomicAdd(sum, 0.f);
      int   c = atomicAdd(cnt, 0);
      if (c < 1) c = 1;
      out[0] = s / (float)c;
    }
  }
}

extern "C" void kernel_launch(void* const* d_in, const int* in_sizes, int n_in,
                              void* d_out, int out_size, void* d_ws, size_t ws_size,
                              hipStream_t stream) {
  const float* x   = (const float*)d_in[0];
  const int*   lab = (const int*)d_in[1];
  float*       out = (float*)d_out;

  char* ws = (char*)d_ws;
  unsigned short* xhf = (unsigned short*)ws;                      // 4 MB (+512 KB slack)
  float* sqq = (float*)(ws + (size_t)4608 * 1024);                // 32 KB
  char*  pb = ws + (size_t)4608 * 1024 + 65536;
  size_t seg = (size_t)NP * B_N * 4;                              // 512 KB each
  unsigned* pk  = (unsigned*)(pb + 0 * seg);
  unsigned* nk  = (unsigned*)(pb + 1 * seg);
  float* sum  = (float*)(pb + 2 * seg);
  int*   cnt  = (int*)(sum + 1);
  int*   done = (int*)(sum + 2);

  k_split<<<B_N / 16, 256, 0, stream>>>(x, xhf, sqq, sum, cnt, done);
  dim3 g(B_N / 128, 8);
  k_mine7<<<g, 256, 0, stream>>>(xhf, lab, sqq, pk, nk);
  k_finish<<<256, 256, 0, stream>>>(x, pk, nk, sum, cnt, done, out);
}

// Round 9
// 159.589 us; speedup vs baseline: 1.1421x; 1.0331x over previous
//
#include <hip/hip_runtime.h>
#include <math.h>

// EnhancedTripletLoss, B=8192, D=256, 8 classes.
// R9: R7 4-dispatch skeleton (known-good) + amdgpu_waves_per_eu(2,2) on the
// mine kernel to unlock the 256-VGPR budget (64KB LDS already caps the CU at
// 2 blocks, so targeting 2 waves/EU costs nothing) + depth-1 named prefetch
// of BOTH A (LDS) and B (global) fragments.
// Selection on v = sq_j - 2*dot via packed keys (q(v)<<13)|j; exact fp32
// recompute of mined triplet distances (F.pairwise_distance eps semantics).

typedef __attribute__((ext_vector_type(8))) short short8;
typedef __attribute__((ext_vector_type(4))) float floatx4;

#define B_N 8192
#define D_K 256
#define NP  16

__device__ __forceinline__ unsigned short f2bf_rne(float f) {
  unsigned u = __float_as_uint(f);
  u += 0x7FFFu + ((u >> 16) & 1u);
  return (unsigned short)(u >> 16);
}

// ---- split to bf16 fragment-major + quantized row norms + zero accums ----
// Tile (16 rows x 32 k) = 512 ushorts at [tile_row][tk][lane*8+j]:
// lane = quad*16 + m, row = 16*tile_row + m, k = 32*tk + quad*8 + j.
__global__ void k_split(const float* __restrict__ x, unsigned short* __restrict__ xhf,
                        float* __restrict__ sqq, float* __restrict__ sum,
                        int* __restrict__ cnt, int* __restrict__ done) {
  __shared__ float sw[64];
  const int tid  = threadIdx.x;
  const int lane = tid & 63;
  const int w    = tid >> 6;
  const int b    = blockIdx.x;        // tile_row
  const int m    = lane & 15;
  const int quad = lane >> 4;
  const int row  = b * 16 + m;

  float s = 0.f;
#pragma unroll
  for (int h = 0; h < 2; ++h) {
    int tk = w + h * 4;
    int kk = tk * 32 + quad * 8;
    float4 f0 = *reinterpret_cast<const float4*>(x + (size_t)row * D_K + kk);
    float4 f1 = *reinterpret_cast<const float4*>(x + (size_t)row * D_K + kk + 4);
    s += f0.x * f0.x + f0.y * f0.y + f0.z * f0.z + f0.w * f0.w;
    s += f1.x * f1.x + f1.y * f1.y + f1.z * f1.z + f1.w * f1.w;
    ushort4 lo, hi;
    lo.x = f2bf_rne(f0.x); lo.y = f2bf_rne(f0.y); lo.z = f2bf_rne(f0.z); lo.w = f2bf_rne(f0.w);
    hi.x = f2bf_rne(f1.x); hi.y = f2bf_rne(f1.y); hi.z = f2bf_rne(f1.z); hi.w = f2bf_rne(f1.w);
    size_t o = ((size_t)b * 8 + tk) * 512 + lane * 8;
    *reinterpret_cast<ushort4*>(xhf + o)     = lo;
    *reinterpret_cast<ushort4*>(xhf + o + 4) = hi;
  }
  s += __shfl_xor(s, 16);
  s += __shfl_xor(s, 32);
  if (quad == 0) sw[w * 16 + m] = s;
  __syncthreads();
  if (tid < 16) {
    float t = sw[tid] + sw[16 + tid] + sw[32 + tid] + sw[48 + tid];
    sqq[b * 16 + tid] = fmaf(t, 128.f, 262144.f);   // pre-quantized for key calc
  }
  if (b == 0 && tid == 0) { *sum = 0.f; *cnt = 0; *done = 0; }
}

// ---- MFMA Gram + hard mining: A in LDS, A+B depth-1 prefetch, 256-reg budget ----
__global__ __launch_bounds__(256)
__attribute__((amdgpu_waves_per_eu(2, 2)))
void k_mine9(
    const unsigned short* __restrict__ xhf, const int* __restrict__ lab,
    const float* __restrict__ sqq,
    unsigned* __restrict__ pk, unsigned* __restrict__ nk) {
  __shared__ unsigned short Alds[8 * 8 * 512];   // 64 KB: [mtile 8][tk 8][512]

  const int tid  = threadIdx.x;
  const int lane = tid & 63;
  const int w    = tid >> 6;
  const int wi   = w >> 1, wj = w & 1;
  const int quad = lane >> 4, l15 = lane & 15;
  const int i0   = blockIdx.x * 128;
  const int by   = blockIdx.y;

  // stage A: one contiguous 64 KB copy (already fragment-major)
  {
    const short8* src = reinterpret_cast<const short8*>(xhf + (size_t)blockIdx.x * 32768);
    short8* dst = reinterpret_cast<short8*>(Alds);
#pragma unroll
    for (int it = 0; it < 16; ++it) dst[it * 256 + tid] = src[it * 256 + tid];
  }

  unsigned pkey[16], nkey[16];
  unsigned lip0 = 0, lip1 = 0;
#pragma unroll
  for (int r = 0; r < 16; ++r) {
    pkey[r] = 0u; nkey[r] = 0xFFFFFFFFu;
    int ir = i0 + wi * 64 + (r >> 2) * 16 + quad * 4 + (r & 3);
    unsigned lv = (unsigned)lab[ir] & 0xFu;
    if (r < 8) lip0 |= lv << (r * 4); else lip1 |= lv << ((r - 8) * 4);
  }
  __syncthreads();   // the only barrier

  const unsigned short* Bw = xhf + ((size_t)(by * 64 + wj * 4) * 8) * 512 + lane * 8;
  const unsigned short* Aw = Alds + (size_t)wi * 32 * 512 + lane * 8;

  short8 Bf[4], Bn[4], Af[4], An[4];
#pragma unroll
  for (int nt = 0; nt < 4; ++nt)
    Bf[nt] = *reinterpret_cast<const short8*>(Bw + nt * 4096);
#pragma unroll
  for (int mt = 0; mt < 4; ++mt)
    Af[mt] = *reinterpret_cast<const short8*>(Aw + (size_t)mt * 8 * 512);

  for (int sub = 0; sub < 8; ++sub) {
    const unsigned short* Bs = Bw + (size_t)sub * 32768;
    floatx4 acc[16];
#pragma unroll
    for (int q = 0; q < 16; ++q) acc[q] = (floatx4)0.f;

#pragma unroll
    for (int tk = 0; tk < 8; ++tk) {
      // prefetch t+1's B frags (tk==7 -> next sub's tk0; sub==7 reads slack)
      const int c = tk + 1;
      const unsigned short* Bp = Bs + (c < 8 ? c * 512 : 32768);
#pragma unroll
      for (int nt = 0; nt < 4; ++nt)
        Bn[nt] = *reinterpret_cast<const short8*>(Bp + nt * 4096);
      // prefetch t+1's A frags (A is sub-invariant: tk==7 wraps to tk0)
      const int atk = c & 7;
#pragma unroll
      for (int mt = 0; mt < 4; ++mt)
        An[mt] = *reinterpret_cast<const short8*>(Aw + (size_t)(mt * 8 + atk) * 512);

#pragma unroll
      for (int mt = 0; mt < 4; ++mt)
#pragma unroll
        for (int nt = 0; nt < 4; ++nt)
          acc[mt * 4 + nt] = __builtin_amdgcn_mfma_f32_16x16x32_bf16(
              Af[mt], Bf[nt], acc[mt * 4 + nt], 0, 0, 0);

#pragma unroll
      for (int q = 0; q < 4; ++q) { Bf[q] = Bn[q]; Af[q] = An[q]; }
    }

    // selection on v = sq_j - 2*dot; key = (cvt(sjq - 256*dot) << 13) | j.
    // Self never wins argmax-pos (its v = -sq_i is the per-row minimum).
    const int j0 = by * 1024 + sub * 128;
#pragma unroll
    for (int nt = 0; nt < 4; ++nt) {
      int      j  = j0 + wj * 64 + nt * 16 + l15;
      unsigned jl = (unsigned)lab[j] & 0xFu;
      float    sj = sqq[j];
#pragma unroll
      for (int r = 0; r < 16; ++r) {
        int mt = r >> 2, reg = r & 3;
        unsigned kq  = (unsigned)fmaf(-256.f, acc[mt * 4 + nt][reg], sj);
        unsigned key = (kq << 13) | (unsigned)j;
        unsigned lr  = (r < 8 ? (lip0 >> (r * 4)) : (lip1 >> ((r - 8) * 4))) & 0xFu;
        bool eq = (jl == lr);
        unsigned pc = eq ? key : 0u;
        unsigned nc = eq ? 0xFFFFFFFFu : key;
        pkey[r] = pkey[r] > pc ? pkey[r] : pc;
        nkey[r] = nkey[r] < nc ? nkey[r] : nc;
      }
    }
  }

  // reduce across the 16 l15-lanes of each quad
#pragma unroll
  for (int r = 0; r < 16; ++r) {
    unsigned p = pkey[r], n = nkey[r];
#pragma unroll
    for (int m = 1; m < 16; m <<= 1) {
      unsigned op = (unsigned)__shfl_xor((int)p, m);
      unsigned on = (unsigned)__shfl_xor((int)n, m);
      p = p > op ? p : op;
      n = n < on ? n : on;
    }
    if (l15 == 0) {
      int ir = i0 + wi * 64 + (r >> 2) * 16 + quad * 4 + (r & 3);
      size_t idx = (size_t)(by * 2 + wj) * B_N + ir;
      pk[idx] = p;
      nk[idx] = n;
    }
  }
}

// ---- reduce partials + exact fp32 triplet distances + loss + final divide ----
__global__ void k_finish(const float* __restrict__ x,
                         const unsigned* __restrict__ pk, const unsigned* __restrict__ nk,
                         float* __restrict__ sum, int* __restrict__ cnt,
                         int* __restrict__ done, float* __restrict__ out) {
  __shared__ float ssum[4];
  __shared__ int   scnt[4];
  int w = threadIdx.x >> 6, lane = threadIdx.x & 63;
  float lsum = 0.f; int lcnt = 0;
  for (int it = 0; it < 8; ++it) {
    int a = (blockIdx.x * 4 + w) * 8 + it;
    unsigned p = 0u, n = 0xFFFFFFFFu;
    if (lane < NP) {
      p = pk[(size_t)lane * B_N + a];
      n = nk[(size_t)lane * B_N + a];
    }
#pragma unroll
    for (int m = 1; m < 16; m <<= 1) {
      unsigned op = (unsigned)__shfl_xor((int)p, m);
      unsigned on = (unsigned)__shfl_xor((int)n, m);
      p = p > op ? p : op;
      n = n < on ? n : on;
    }
    p = (unsigned)__shfl((int)p, 0);
    n = (unsigned)__shfl((int)n, 0);
    bool valid = (p != 0u) && (n != 0xFFFFFFFFu);
    int  pidx = valid ? (int)(p & 8191u) : 0;
    int  nidx = valid ? (int)(n & 8191u) : 0;

    float4 xa = *reinterpret_cast<const float4*>(x + (size_t)a * D_K + lane * 4);
    float4 xp = *reinterpret_cast<const float4*>(x + (size_t)pidx * D_K + lane * 4);
    float4 xn = *reinterpret_cast<const float4*>(x + (size_t)nidx * D_K + lane * 4);
    float dx, sp = 0.f, sn = 0.f;
    dx = xa.x - xp.x + 1e-6f; sp = fmaf(dx, dx, sp);
    dx = xa.y - xp.y + 1e-6f; sp = fmaf(dx, dx, sp);
    dx = xa.z - xp.z + 1e-6f; sp = fmaf(dx, dx, sp);
    dx = xa.w - xp.w + 1e-6f; sp = fmaf(dx, dx, sp);
    dx = xa.x - xn.x + 1e-6f; sn = fmaf(dx, dx, sn);
    dx = xa.y - xn.y + 1e-6f; sn = fmaf(dx, dx, sn);
    dx = xa.z - xn.z + 1e-6f; sn = fmaf(dx, dx, sn);
    dx = xa.w - xn.w + 1e-6f; sn = fmaf(dx, dx, sn);
#pragma unroll
    for (int o = 32; o > 0; o >>= 1) {
      sp += __shfl_down(sp, o, 64);
      sn += __shfl_down(sn, o, 64);
    }
    if (lane == 0 && valid) {
      float per = sqrtf(sp) - sqrtf(sn) + 0.3f;
      if (per > 0.f) lsum += per;
      lcnt += 1;
    }
  }
  if (lane == 0) { ssum[w] = lsum; scnt[w] = lcnt; }
  __syncthreads();
  if (threadIdx.x == 0) {
    atomicAdd(sum, ssum[0] + ssum[1] + ssum[2] + ssum[3]);
    atomicAdd(cnt, scnt[0] + scnt[1] + scnt[2] + scnt[3]);
    __threadfence();
    int prev = atomicAdd(done, 1);
    if (prev == gridDim.x - 1) {
      float s = atomicAdd(sum, 0.f);
      int   c = atomicAdd(cnt, 0);
      if (c < 1) c = 1;
      out[0] = s / (float)c;
    }
  }
}

extern "C" void kernel_launch(void* const* d_in, const int* in_sizes, int n_in,
                              void* d_out, int out_size, void* d_ws, size_t ws_size,
                              hipStream_t stream) {
  const float* x   = (const float*)d_in[0];
  const int*   lab = (const int*)d_in[1];
  float*       out = (float*)d_out;

  char* ws = (char*)d_ws;
  unsigned short* xhf = (unsigned short*)ws;                      // 4 MB (+512 KB slack)
  float* sqq = (float*)(ws + (size_t)4608 * 1024);                // 32 KB
  char*  pb = ws + (size_t)4608 * 1024 + 65536;
  size_t seg = (size_t)NP * B_N * 4;                              // 512 KB each
  unsigned* pk  = (unsigned*)(pb + 0 * seg);
  unsigned* nk  = (unsigned*)(pb + 1 * seg);
  float* sum  = (float*)(pb + 2 * seg);
  int*   cnt  = (int*)(sum + 1);
  int*   done = (int*)(sum + 2);

  k_split<<<B_N / 16, 256, 0, stream>>>(x, xhf, sqq, sum, cnt, done);
  dim3 g(B_N / 128, 8);
  k_mine9<<<g, 256, 0, stream>>>(xhf, lab, sqq, pk, nk);
  k_finish<<<256, 256, 0, stream>>>(x, pk, nk, sum, cnt, done, out);
}

// Round 10
// 156.296 us; speedup vs baseline: 1.1662x; 1.0211x over previous
//
#include <hip/hip_runtime.h>
#include <math.h>

// EnhancedTripletLoss, B=8192, D=256, 8 classes.
// R10: occupancy attack. TI=64 anchors/block -> A-LDS 32 KB -> 4 blocks/CU
// x 4 waves = 16 waves/CU (4/SIMD, was 2). Wave tile 32x64 (acc=32 AGPRs),
// 256-thread blocks (compiler reliably grants 128 arch VGPRs; ~117 live).
// No manual prefetch: wave-level TLP hides ds_read/L2 latency (m97 model).
// Selection on v = sq_j - 2*dot via packed keys (q(v)<<13)|j; exact fp32
// recompute of mined triplet distances in k_finish.

typedef __attribute__((ext_vector_type(8))) short short8;
typedef __attribute__((ext_vector_type(4))) float floatx4;

#define B_N 8192
#define D_K 256
#define NP  16

__device__ __forceinline__ unsigned short f2bf_rne(float f) {
  unsigned u = __float_as_uint(f);
  u += 0x7FFFu + ((u >> 16) & 1u);
  return (unsigned short)(u >> 16);
}

// ---- split to bf16 fragment-major + quantized row norms + zero accums ----
// Tile (16 rows x 32 k) = 512 ushorts at [tile_row][tk][lane*8+j]:
// lane = quad*16 + m, row = 16*tile_row + m, k = 32*tk + quad*8 + j.
__global__ void k_split(const float* __restrict__ x, unsigned short* __restrict__ xhf,
                        float* __restrict__ sqq, float* __restrict__ sum,
                        int* __restrict__ cnt, int* __restrict__ done) {
  __shared__ float sw[64];
  const int tid  = threadIdx.x;
  const int lane = tid & 63;
  const int w    = tid >> 6;
  const int b    = blockIdx.x;        // tile_row
  const int m    = lane & 15;
  const int quad = lane >> 4;
  const int row  = b * 16 + m;

  float s = 0.f;
#pragma unroll
  for (int h = 0; h < 2; ++h) {
    int tk = w + h * 4;
    int kk = tk * 32 + quad * 8;
    float4 f0 = *reinterpret_cast<const float4*>(x + (size_t)row * D_K + kk);
    float4 f1 = *reinterpret_cast<const float4*>(x + (size_t)row * D_K + kk + 4);
    s += f0.x * f0.x + f0.y * f0.y + f0.z * f0.z + f0.w * f0.w;
    s += f1.x * f1.x + f1.y * f1.y + f1.z * f1.z + f1.w * f1.w;
    ushort4 lo, hi;
    lo.x = f2bf_rne(f0.x); lo.y = f2bf_rne(f0.y); lo.z = f2bf_rne(f0.z); lo.w = f2bf_rne(f0.w);
    hi.x = f2bf_rne(f1.x); hi.y = f2bf_rne(f1.y); hi.z = f2bf_rne(f1.z); hi.w = f2bf_rne(f1.w);
    size_t o = ((size_t)b * 8 + tk) * 512 + lane * 8;
    *reinterpret_cast<ushort4*>(xhf + o)     = lo;
    *reinterpret_cast<ushort4*>(xhf + o + 4) = hi;
  }
  s += __shfl_xor(s, 16);
  s += __shfl_xor(s, 32);
  if (quad == 0) sw[w * 16 + m] = s;
  __syncthreads();
  if (tid < 16) {
    float t = sw[tid] + sw[16 + tid] + sw[32 + tid] + sw[48 + tid];
    sqq[b * 16 + tid] = fmaf(t, 128.f, 262144.f);   // pre-quantized for key calc
  }
  if (b == 0 && tid == 0) { *sum = 0.f; *cnt = 0; *done = 0; }
}

// ---- MFMA Gram + hard mining: 32 KB A-LDS, 4 blocks/CU, wave tile 32x64 ----
__global__ __launch_bounds__(256) void k_mine10(
    const unsigned short* __restrict__ xhf, const int* __restrict__ lab,
    const float* __restrict__ sqq,
    unsigned* __restrict__ pk, unsigned* __restrict__ nk) {
  __shared__ unsigned short Alds[4 * 8 * 512];   // 32 KB: [mtile 4][tk 8][512]

  const int tid  = threadIdx.x;
  const int lane = tid & 63;
  const int w    = tid >> 6;
  const int wi   = w >> 1, wj = w & 1;   // wi: 32-anchor band, wj: 64-j half
  const int quad = lane >> 4, l15 = lane & 15;
  const int i0   = blockIdx.x * 64;
  const int by   = blockIdx.y;

  // stage A: one contiguous 32 KB copy (already fragment-major)
  {
    const short8* src = reinterpret_cast<const short8*>(xhf + (size_t)blockIdx.x * 16384);
    short8* dst = reinterpret_cast<short8*>(Alds);
#pragma unroll
    for (int it = 0; it < 8; ++it) dst[it * 256 + tid] = src[it * 256 + tid];
  }

  unsigned pkey[8], nkey[8];
  unsigned lip = 0;                      // 8 row labels, 4 bits each
#pragma unroll
  for (int r = 0; r < 8; ++r) {
    pkey[r] = 0u; nkey[r] = 0xFFFFFFFFu;
    int ir = i0 + wi * 32 + (r >> 2) * 16 + quad * 4 + (r & 3);
    lip |= ((unsigned)lab[ir] & 0xFu) << (r * 4);
  }
  __syncthreads();   // the only barrier

  const unsigned short* Bw = xhf + ((size_t)(by * 64 + wj * 4) * 8) * 512 + lane * 8;
  const unsigned short* Aw = Alds + (size_t)(wi * 2) * 8 * 512 + lane * 8;

  for (int sub = 0; sub < 8; ++sub) {
    const unsigned short* Bs = Bw + (size_t)sub * 32768;
    floatx4 acc[8];
#pragma unroll
    for (int q = 0; q < 8; ++q) acc[q] = (floatx4)0.f;

#pragma unroll
    for (int tk = 0; tk < 8; ++tk) {
      short8 Bf[4];
#pragma unroll
      for (int nt = 0; nt < 4; ++nt)
        Bf[nt] = *reinterpret_cast<const short8*>(Bs + nt * 4096 + tk * 512);
      short8 Af[2];
#pragma unroll
      for (int mt = 0; mt < 2; ++mt)
        Af[mt] = *reinterpret_cast<const short8*>(Aw + (size_t)(mt * 8 + tk) * 512);
#pragma unroll
      for (int mt = 0; mt < 2; ++mt)
#pragma unroll
        for (int nt = 0; nt < 4; ++nt)
          acc[mt * 4 + nt] = __builtin_amdgcn_mfma_f32_16x16x32_bf16(
              Af[mt], Bf[nt], acc[mt * 4 + nt], 0, 0, 0);
    }

    // selection on v = sq_j - 2*dot; key = (cvt(sjq - 256*dot) << 13) | j.
    // Self never wins argmax-pos (its v = -sq_i is the per-row minimum).
    const int j0 = by * 1024 + sub * 128 + wj * 64;
#pragma unroll
    for (int nt = 0; nt < 4; ++nt) {
      int      j  = j0 + nt * 16 + l15;
      unsigned jl = (unsigned)lab[j] & 0xFu;
      float    sj = sqq[j];
#pragma unroll
      for (int r = 0; r < 8; ++r) {
        int mt = r >> 2, reg = r & 3;
        unsigned kq  = (unsigned)fmaf(-256.f, acc[mt * 4 + nt][reg], sj);
        unsigned key = (kq << 13) | (unsigned)j;
        bool eq = (jl == ((lip >> (r * 4)) & 0xFu));
        unsigned pc = eq ? key : 0u;
        unsigned nc = eq ? 0xFFFFFFFFu : key;
        pkey[r] = pkey[r] > pc ? pkey[r] : pc;
        nkey[r] = nkey[r] < nc ? nkey[r] : nc;
      }
    }
  }

  // reduce across the 16 l15-lanes of each quad
#pragma unroll
  for (int r = 0; r < 8; ++r) {
    unsigned p = pkey[r], n = nkey[r];
#pragma unroll
    for (int m = 1; m < 16; m <<= 1) {
      unsigned op = (unsigned)__shfl_xor((int)p, m);
      unsigned on = (unsigned)__shfl_xor((int)n, m);
      p = p > op ? p : op;
      n = n < on ? n : on;
    }
    if (l15 == 0) {
      int ir = i0 + wi * 32 + (r >> 2) * 16 + quad * 4 + (r & 3);
      size_t idx = (size_t)(by * 2 + wj) * B_N + ir;
      pk[idx] = p;
      nk[idx] = n;
    }
  }
}

// ---- reduce partials + exact fp32 triplet distances + loss + final divide ----
__global__ void k_finish(const float* __restrict__ x,
                         const unsigned* __restrict__ pk, const unsigned* __restrict__ nk,
                         float* __restrict__ sum, int* __restrict__ cnt,
                         int* __restrict__ done, float* __restrict__ out) {
  __shared__ float ssum[4];
  __shared__ int   scnt[4];
  int w = threadIdx.x >> 6, lane = threadIdx.x & 63;
  float lsum = 0.f; int lcnt = 0;
  for (int it = 0; it < 8; ++it) {
    int a = (blockIdx.x * 4 + w) * 8 + it;
    unsigned p = 0u, n = 0xFFFFFFFFu;
    if (lane < NP) {
      p = pk[(size_t)lane * B_N + a];
      n = nk[(size_t)lane * B_N + a];
    }
#pragma unroll
    for (int m = 1; m < 16; m <<= 1) {
      unsigned op = (unsigned)__shfl_xor((int)p, m);
      unsigned on = (unsigned)__shfl_xor((int)n, m);
      p = p > op ? p : op;
      n = n < on ? n : on;
    }
    p = (unsigned)__shfl((int)p, 0);
    n = (unsigned)__shfl((int)n, 0);
    bool valid = (p != 0u) && (n != 0xFFFFFFFFu);
    int  pidx = valid ? (int)(p & 8191u) : 0;
    int  nidx = valid ? (int)(n & 8191u) : 0;

    float4 xa = *reinterpret_cast<const float4*>(x + (size_t)a * D_K + lane * 4);
    float4 xp = *reinterpret_cast<const float4*>(x + (size_t)pidx * D_K + lane * 4);
    float4 xn = *reinterpret_cast<const float4*>(x + (size_t)nidx * D_K + lane * 4);
    float dx, sp = 0.f, sn = 0.f;
    dx = xa.x - xp.x + 1e-6f; sp = fmaf(dx, dx, sp);
    dx = xa.y - xp.y + 1e-6f; sp = fmaf(dx, dx, sp);
    dx = xa.z - xp.z + 1e-6f; sp = fmaf(dx, dx, sp);
    dx = xa.w - xp.w + 1e-6f; sp = fmaf(dx, dx, sp);
    dx = xa.x - xn.x + 1e-6f; sn = fmaf(dx, dx, sn);
    dx = xa.y - xn.y + 1e-6f; sn = fmaf(dx, dx, sn);
    dx = xa.z - xn.z + 1e-6f; sn = fmaf(dx, dx, sn);
    dx = xa.w - xn.w + 1e-6f; sn = fmaf(dx, dx, sn);
#pragma unroll
    for (int o = 32; o > 0; o >>= 1) {
      sp += __shfl_down(sp, o, 64);
      sn += __shfl_down(sn, o, 64);
    }
    if (lane == 0 && valid) {
      float per = sqrtf(sp) - sqrtf(sn) + 0.3f;
      if (per > 0.f) lsum += per;
      lcnt += 1;
    }
  }
  if (lane == 0) { ssum[w] = lsum; scnt[w] = lcnt; }
  __syncthreads();
  if (threadIdx.x == 0) {
    atomicAdd(sum, ssum[0] + ssum[1] + ssum[2] + ssum[3]);
    atomicAdd(cnt, scnt[0] + scnt[1] + scnt[2] + scnt[3]);
    __threadfence();
    int prev = atomicAdd(done, 1);
    if (prev == gridDim.x - 1) {
      float s = atomicAdd(sum, 0.f);
      int   c = atomicAdd(cnt, 0);
      if (c < 1) c = 1;
      out[0] = s / (float)c;
    }
  }
}

extern "C" void kernel_launch(void* const* d_in, const int* in_sizes, int n_in,
                              void* d_out, int out_size, void* d_ws, size_t ws_size,
                              hipStream_t stream) {
  const float* x   = (const float*)d_in[0];
  const int*   lab = (const int*)d_in[1];
  float*       out = (float*)d_out;

  char* ws = (char*)d_ws;
  unsigned short* xhf = (unsigned short*)ws;                      // 4 MB (+512 KB slack)
  float* sqq = (float*)(ws + (size_t)4608 * 1024);                // 32 KB
  char*  pb = ws + (size_t)4608 * 1024 + 65536;
  size_t seg = (size_t)NP * B_N * 4;                              // 512 KB each
  unsigned* pk  = (unsigned*)(pb + 0 * seg);
  unsigned* nk  = (unsigned*)(pb + 1 * seg);
  float* sum  = (float*)(pb + 2 * seg);
  int*   cnt  = (int*)(sum + 1);
  int*   done = (int*)(sum + 2);

  k_split<<<B_N / 16, 256, 0, stream>>>(x, xhf, sqq, sum, cnt, done);
  dim3 g(B_N / 64, 8);
  k_mine10<<<g, 256, 0, stream>>>(xhf, lab, sqq, pk, nk);
  k_finish<<<256, 256, 0, stream>>>(x, pk, nk, sum, cnt, done, out);
}

// Round 11
// 153.790 us; speedup vs baseline: 1.1852x; 1.0163x over previous
//
#include <hip/hip_runtime.h>
#include <math.h>

// EnhancedTripletLoss, B=8192, D=256, 8 classes.
// R11: TRIANGULAR mining — D(i,j)=D(j,i), so each 128x128 block-pair tile
// (bi<=bj, 2080 blocks) updates BOTH i-row and j-row selections from one
// Gram computation (j-side uses v_ji = sq_i - 2*dot with the same eq mask).
// ~2x less MFMA / B-traffic / epilogue than full-matrix sweep.
// Selection via global atomicMax/atomicMin on packed u32 keys (q(v)<<13)|idx.
// Exact fp32 recompute of mined triplet distances in k_finish.

typedef __attribute__((ext_vector_type(8))) short short8;
typedef __attribute__((ext_vector_type(4))) float floatx4;

#define B_N 8192
#define D_K 256

__device__ __forceinline__ unsigned short f2bf_rne(float f) {
  unsigned u = __float_as_uint(f);
  u += 0x7FFFu + ((u >> 16) & 1u);
  return (unsigned short)(u >> 16);
}

// ---- split to bf16 fragment-major + quantized row norms + init keys ----
// Tile (16 rows x 32 k) = 512 ushorts at [tile_row][tk][lane*8+j]:
// lane = quad*16 + m, row = 16*tile_row + m, k = 32*tk + quad*8 + j.
__global__ void k_split(const float* __restrict__ x, unsigned short* __restrict__ xhf,
                        float* __restrict__ sqq,
                        unsigned* __restrict__ pk, unsigned* __restrict__ nk,
                        float* __restrict__ sum, int* __restrict__ cnt,
                        int* __restrict__ done) {
  __shared__ float sw[64];
  const int tid  = threadIdx.x;
  const int lane = tid & 63;
  const int w    = tid >> 6;
  const int b    = blockIdx.x;        // tile_row
  const int m    = lane & 15;
  const int quad = lane >> 4;
  const int row  = b * 16 + m;

  float s = 0.f;
#pragma unroll
  for (int h = 0; h < 2; ++h) {
    int tk = w + h * 4;
    int kk = tk * 32 + quad * 8;
    float4 f0 = *reinterpret_cast<const float4*>(x + (size_t)row * D_K + kk);
    float4 f1 = *reinterpret_cast<const float4*>(x + (size_t)row * D_K + kk + 4);
    s += f0.x * f0.x + f0.y * f0.y + f0.z * f0.z + f0.w * f0.w;
    s += f1.x * f1.x + f1.y * f1.y + f1.z * f1.z + f1.w * f1.w;
    ushort4 lo, hi;
    lo.x = f2bf_rne(f0.x); lo.y = f2bf_rne(f0.y); lo.z = f2bf_rne(f0.z); lo.w = f2bf_rne(f0.w);
    hi.x = f2bf_rne(f1.x); hi.y = f2bf_rne(f1.y); hi.z = f2bf_rne(f1.z); hi.w = f2bf_rne(f1.w);
    size_t o = ((size_t)b * 8 + tk) * 512 + lane * 8;
    *reinterpret_cast<ushort4*>(xhf + o)     = lo;
    *reinterpret_cast<ushort4*>(xhf + o + 4) = hi;
  }
  s += __shfl_xor(s, 16);
  s += __shfl_xor(s, 32);
  if (quad == 0) sw[w * 16 + m] = s;
  __syncthreads();
  if (tid < 16) {
    int i = b * 16 + tid;
    float t = sw[tid] + sw[16 + tid] + sw[32 + tid] + sw[48 + tid];
    sqq[i] = fmaf(t, 128.f, 262144.f);   // pre-quantized for key calc
    pk[i] = 0u;                          // selection-key init
    nk[i] = 0xFFFFFFFFu;
  }
  if (b == 0 && tid == 0) { *sum = 0.f; *cnt = 0; *done = 0; }
}

// ---- MFMA Gram + two-sided hard mining over the upper triangle ----
__global__ __launch_bounds__(256) void k_mine11(
    const unsigned short* __restrict__ xhf, const int* __restrict__ lab,
    const float* __restrict__ sqq,
    unsigned* __restrict__ pk, unsigned* __restrict__ nk) {
  __shared__ unsigned short Alds[8 * 8 * 512];   // 64 KB: [mtile 8][tk 8][512]

  // decode linear block id -> (bi, bj), bi <= bj, over 64x64 block grid
  int t  = blockIdx.x;
  int bi = (int)(64.5f - sqrtf(64.5f * 64.5f - 2.f * (float)t));
  int b0 = 64 * bi - (bi * (bi - 1)) / 2;
  if (t < b0) { bi--; b0 = 64 * bi - (bi * (bi - 1)) / 2; }
  else {
    int b1 = 64 * (bi + 1) - ((bi + 1) * bi) / 2;
    if (t >= b1) { bi++; b0 = b1; }
  }
  const int bj = bi + (t - b0);

  const int tid  = threadIdx.x;
  const int lane = tid & 63;
  const int w    = tid >> 6;
  const int wi   = w >> 1, wj = w & 1;
  const int quad = lane >> 4, l15 = lane & 15;
  const int i0   = bi * 128;

  // stage A: one contiguous 64 KB copy (already fragment-major)
  {
    const short8* src = reinterpret_cast<const short8*>(xhf + (size_t)bi * 32768);
    short8* dst = reinterpret_cast<short8*>(Alds);
#pragma unroll
    for (int it = 0; it < 16; ++it) dst[it * 256 + tid] = src[it * 256 + tid];
  }

  // per-anchor-row state: r = mt*4+reg -> ir = i0 + wi*64 + mt*16 + quad*4 + reg
  unsigned pkey[16], nkey[16];
  unsigned lip0 = 0, lip1 = 0;
  float    sqi[16];
#pragma unroll
  for (int r = 0; r < 16; ++r) {
    pkey[r] = 0u; nkey[r] = 0xFFFFFFFFu;
    int ir = i0 + wi * 64 + (r >> 2) * 16 + quad * 4 + (r & 3);
    unsigned lv = (unsigned)lab[ir] & 0xFu;
    if (r < 8) lip0 |= lv << (r * 4); else lip1 |= lv << ((r - 8) * 4);
    sqi[r] = sqq[ir];
  }
  __syncthreads();   // the only barrier

  const unsigned short* Bw = xhf + ((size_t)(bj * 8 + wj * 4) * 8) * 512 + lane * 8;
  const unsigned short* Aw = Alds + (size_t)wi * 32 * 512 + lane * 8;

  floatx4 acc[16];
#pragma unroll
  for (int q = 0; q < 16; ++q) acc[q] = (floatx4)0.f;

#pragma unroll
  for (int tk = 0; tk < 8; ++tk) {
    short8 Bf[4];
#pragma unroll
    for (int nt = 0; nt < 4; ++nt)
      Bf[nt] = *reinterpret_cast<const short8*>(Bw + nt * 4096 + tk * 512);
    short8 Af[4];
#pragma unroll
    for (int mt = 0; mt < 4; ++mt)
      Af[mt] = *reinterpret_cast<const short8*>(Aw + (size_t)(mt * 8 + tk) * 512);
#pragma unroll
    for (int mt = 0; mt < 4; ++mt)
#pragma unroll
      for (int nt = 0; nt < 4; ++nt)
        acc[mt * 4 + nt] = __builtin_amdgcn_mfma_f32_16x16x32_bf16(
            Af[mt], Bf[nt], acc[mt * 4 + nt], 0, 0, 0);
  }

  // two-sided selection epilogue.
  // i-side: v_ij = sq_j - 2*dot -> key (cvt(sjq-256*dot)<<13)|j, umax/umin.
  // j-side: v_ji = sq_i - 2*dot -> key (cvt(sqi-256*dot)<<13)|i, same eq.
  // Diagonal blocks double-update: idempotent for max/min. Self-pair never
  // wins argmax-pos (its v = -sq is the per-row minimum).
#pragma unroll
  for (int nt = 0; nt < 4; ++nt) {
    int      j  = bj * 128 + wj * 64 + nt * 16 + l15;
    unsigned jl = (unsigned)lab[j] & 0xFu;
    float    sj = sqq[j];
    unsigned jp = 0u, jn = 0xFFFFFFFFu;
#pragma unroll
    for (int r = 0; r < 16; ++r) {
      int mt = r >> 2, reg = r & 3;
      float dot = acc[mt * 4 + nt][reg];
      int   ir  = i0 + wi * 64 + mt * 16 + quad * 4 + reg;
      unsigned lr = (r < 8 ? (lip0 >> (r * 4)) : (lip1 >> ((r - 8) * 4))) & 0xFu;
      bool eq = (jl == lr);
      // i-side
      unsigned kqi  = (unsigned)fmaf(-256.f, dot, sj);
      unsigned keyi = (kqi << 13) | (unsigned)j;
      unsigned pci = eq ? keyi : 0u;
      unsigned nci = eq ? 0xFFFFFFFFu : keyi;
      pkey[r] = pkey[r] > pci ? pkey[r] : pci;
      nkey[r] = nkey[r] < nci ? nkey[r] : nci;
      // j-side
      unsigned kqj  = (unsigned)fmaf(-256.f, dot, sqi[r]);
      unsigned keyj = (kqj << 13) | (unsigned)ir;
      unsigned pcj = eq ? keyj : 0u;
      unsigned ncj = eq ? 0xFFFFFFFFu : keyj;
      jp = jp > pcj ? jp : pcj;
      jn = jn < ncj ? jn : ncj;
    }
    // reduce j-side across the 4 quads sharing this j (lane^16, lane^32)
#pragma unroll
    for (int m = 16; m < 64; m <<= 1) {
      unsigned op = (unsigned)__shfl_xor((int)jp, m);
      unsigned on = (unsigned)__shfl_xor((int)jn, m);
      jp = jp > op ? jp : op;
      jn = jn < on ? jn : on;
    }
    if (quad == 0) {
      if (jp != 0u)          atomicMax(&pk[j], jp);
      if (jn != 0xFFFFFFFFu) atomicMin(&nk[j], jn);
    }
  }

  // reduce i-side across the 16 l15-lanes of each quad
#pragma unroll
  for (int r = 0; r < 16; ++r) {
    unsigned p = pkey[r], n = nkey[r];
#pragma unroll
    for (int m = 1; m < 16; m <<= 1) {
      unsigned op = (unsigned)__shfl_xor((int)p, m);
      unsigned on = (unsigned)__shfl_xor((int)n, m);
      p = p > op ? p : op;
      n = n < on ? n : on;
    }
    if (l15 == 0) {
      int ir = i0 + wi * 64 + (r >> 2) * 16 + quad * 4 + (r & 3);
      if (p != 0u)          atomicMax(&pk[ir], p);
      if (n != 0xFFFFFFFFu) atomicMin(&nk[ir], n);
    }
  }
}

// ---- exact fp32 triplet distances + loss + final divide ----
__global__ void k_finish(const float* __restrict__ x,
                         const unsigned* __restrict__ pk, const unsigned* __restrict__ nk,
                         float* __restrict__ sum, int* __restrict__ cnt,
                         int* __restrict__ done, float* __restrict__ out) {
  __shared__ float ssum[4];
  __shared__ int   scnt[4];
  int w = threadIdx.x >> 6, lane = threadIdx.x & 63;
  float lsum = 0.f; int lcnt = 0;
#pragma unroll
  for (int it = 0; it < 16; ++it) {
    int a = (blockIdx.x * 4 + w) * 16 + it;
    unsigned p = pk[a];
    unsigned n = nk[a];
    bool valid = (p != 0u) && (n != 0xFFFFFFFFu);
    int  pidx = valid ? (int)(p & 8191u) : 0;
    int  nidx = valid ? (int)(n & 8191u) : 0;

    float4 xa = *reinterpret_cast<const float4*>(x + (size_t)a * D_K + lane * 4);
    float4 xp = *reinterpret_cast<const float4*>(x + (size_t)pidx * D_K + lane * 4);
    float4 xn = *reinterpret_cast<const float4*>(x + (size_t)nidx * D_K + lane * 4);
    float dx, sp = 0.f, sn = 0.f;
    dx = xa.x - xp.x + 1e-6f; sp = fmaf(dx, dx, sp);
    dx = xa.y - xp.y + 1e-6f; sp = fmaf(dx, dx, sp);
    dx = xa.z - xp.z + 1e-6f; sp = fmaf(dx, dx, sp);
    dx = xa.w - xp.w + 1e-6f; sp = fmaf(dx, dx, sp);
    dx = xa.x - xn.x + 1e-6f; sn = fmaf(dx, dx, sn);
    dx = xa.y - xn.y + 1e-6f; sn = fmaf(dx, dx, sn);
    dx = xa.z - xn.z + 1e-6f; sn = fmaf(dx, dx, sn);
    dx = xa.w - xn.w + 1e-6f; sn = fmaf(dx, dx, sn);
#pragma unroll
    for (int o = 32; o > 0; o >>= 1) {
      sp += __shfl_down(sp, o, 64);
      sn += __shfl_down(sn, o, 64);
    }
    if (lane == 0 && valid) {
      float per = sqrtf(sp) - sqrtf(sn) + 0.3f;
      if (per > 0.f) lsum += per;
      lcnt += 1;
    }
  }
  if (lane == 0) { ssum[w] = lsum; scnt[w] = lcnt; }
  __syncthreads();
  if (threadIdx.x == 0) {
    atomicAdd(sum, ssum[0] + ssum[1] + ssum[2] + ssum[3]);
    atomicAdd(cnt, scnt[0] + scnt[1] + scnt[2] + scnt[3]);
    __threadfence();
    int prev = atomicAdd(done, 1);
    if (prev == gridDim.x - 1) {
      float s = atomicAdd(sum, 0.f);
      int   c = atomicAdd(cnt, 0);
      if (c < 1) c = 1;
      out[0] = s / (float)c;
    }
  }
}

extern "C" void kernel_launch(void* const* d_in, const int* in_sizes, int n_in,
                              void* d_out, int out_size, void* d_ws, size_t ws_size,
                              hipStream_t stream) {
  const float* x   = (const float*)d_in[0];
  const int*   lab = (const int*)d_in[1];
  float*       out = (float*)d_out;

  char* ws = (char*)d_ws;
  unsigned short* xhf = (unsigned short*)ws;                      // 4 MB
  float* sqq = (float*)(ws + (size_t)4608 * 1024);                // 32 KB
  char*  pb = ws + (size_t)4608 * 1024 + 65536;
  unsigned* pk  = (unsigned*)(pb);                                // 32 KB
  unsigned* nk  = (unsigned*)(pb + 32768);                        // 32 KB
  float* sum  = (float*)(pb + 65536);
  int*   cnt  = (int*)(sum + 1);
  int*   done = (int*)(sum + 2);

  k_split<<<B_N / 16, 256, 0, stream>>>(x, xhf, sqq, pk, nk, sum, cnt, done);
  k_mine11<<<2080, 256, 0, stream>>>(xhf, lab, sqq, pk, nk);
  k_finish<<<128, 256, 0, stream>>>(x, pk, nk, sum, cnt, done, out);
}